// Round 9
// baseline (215.473 us; speedup 1.0000x reference)
//
#include <hip/hip_runtime.h>

// Head attention, B=4 T=4096 C=1024 H=64. f32 in/out, bf16 MFMA compute.
// scores = k @ q^T (reference quirk).
// Counter-backed design rules:
//  - intra-block operand reuse through LDS (r4)
//  - POWER-OF-2 ROW STRIDES CAMP HBM/MALL CHANNELS (r5-r8: 4KB->~1TB/s, 2KB->~0.5,
//    linear->6.4TB/s, L3-residency doesn't help). Pad strides to non-x256B.
//  - scores bounded -> max-free softmax (r8, passed).

typedef __attribute__((ext_vector_type(8))) short short8;
typedef __attribute__((ext_vector_type(4))) float f32x4;
typedef unsigned short u16;

#define XSTR 1048   // xb / Wt row stride (u16): 2096 B, not a multiple of 256 B
#define VSTR 4120   // Vt row stride (u16): 8240 B, not a multiple of 256 B

#define MFMA16(A, B, C) __builtin_amdgcn_mfma_f32_16x16x32_bf16((A), (B), (C), 0, 0, 0)

__device__ __forceinline__ u16 f2b(float f) {
    unsigned int u = __builtin_bit_cast(unsigned int, f);
    u += 0x7fffu + ((u >> 16) & 1u);
    return (u16)(u >> 16);
}
__device__ __forceinline__ float b2f(u16 v) {
    return __builtin_bit_cast(float, (unsigned int)v << 16);
}

// ---------- kernel 0: linear convert x -> xb (bf16, PADDED row stride)
__global__ __launch_bounds__(256) void xconv_kernel(const float* __restrict__ x,
                                                    u16* __restrict__ xb) {
    const int r0 = blockIdx.x * 8;                   // 8 rows per block
    const int tid = threadIdx.x;
#pragma unroll
    for (int i = 0; i < 4; ++i) {
        int lin = i * 2048 + tid * 8;                // 0..8184, 8 elems/thread/iter
        int row = lin >> 10, col = lin & 1023;
        const float* src = x + (size_t)(r0 + row) * 1024 + col;
        float4 a0 = *(const float4*)(src);
        float4 a1 = *(const float4*)(src + 4);
        short8 o;
        o[0] = f2b(a0.x); o[1] = f2b(a0.y); o[2] = f2b(a0.z); o[3] = f2b(a0.w);
        o[4] = f2b(a1.x); o[5] = f2b(a1.y); o[6] = f2b(a1.z); o[7] = f2b(a1.w);
        *(short8*)(xb + (size_t)(r0 + row) * XSTR + col) = o;
    }
}

// ---------- kernel 1: W convert+transpose -> Wt[192][XSTR] bf16
__global__ __launch_bounds__(256) void wt_kernel(const float* __restrict__ Wk,
                                                 const float* __restrict__ Wq,
                                                 const float* __restrict__ Wv,
                                                 u16* __restrict__ Wt) {
    __shared__ u16 t[64][65];
    const int mat = blockIdx.x >> 4;
    const int rt  = blockIdx.x & 15;
    const float* W = (mat == 0) ? Wk : (mat == 1 ? Wq : Wv);
    const int tid = threadIdx.x;
#pragma unroll
    for (int i = 0; i < 16; ++i) {
        int lin = i * 256 + tid, r = lin >> 6, c = lin & 63;
        t[c][r] = f2b(W[(size_t)(rt * 64 + r) * 64 + c]);
    }
    __syncthreads();
#pragma unroll
    for (int i = 0; i < 16; ++i) {
        int lin = i * 256 + tid, n = lin >> 6, k = lin & 63;
        Wt[(size_t)(mat * 64 + n) * XSTR + rt * 64 + k] = t[n][k];
    }
}

// ---------- kernel 2: proj pass 1 — K-split x4, LDS double-buffered Wt staging,
// bf16 A-frags from padded xb, linear contiguous Pp store.
__global__ __launch_bounds__(256) void proj1_kernel(const u16* __restrict__ xb,
                                                    const u16* __restrict__ Wt,
                                                    u16* __restrict__ Pp) {
    __shared__ u16 smem[2 * 192 * 36];               // 27.6 KB (also epilogue tile)
    const int tid = threadIdx.x;
    const int w = tid >> 6, lane = tid & 63, quad = lane >> 4, l16 = lane & 15;
    const int kchunk = blockIdx.x & 3, mgroup = blockIdx.x >> 2;
    const int mbase = mgroup * 64;
    const int m = mbase + w * 16 + l16;
    const int koff = quad * 8;
    const int kbase = kchunk * 256;

    f32x4 acc[12];
#pragma unroll
    for (int t = 0; t < 12; ++t) acc[t] = (f32x4)(0.0f);

    const u16* xrow = xb + (size_t)m * XSTR + kbase + koff;
    const int u0 = tid, u1 = tid + 256, u2 = tid + 512;  // 768 16B-units = [192][32]

    {   // stage kc=0 into buf 0
        short8 s0 = *(const short8*)(Wt + (size_t)(u0 >> 2) * XSTR + kbase + (u0 & 3) * 8);
        short8 s1 = *(const short8*)(Wt + (size_t)(u1 >> 2) * XSTR + kbase + (u1 & 3) * 8);
        short8 s2 = *(const short8*)(Wt + (size_t)(u2 >> 2) * XSTR + kbase + (u2 & 3) * 8);
        *(short8*)(smem + (u0 >> 2) * 36 + (u0 & 3) * 8) = s0;
        *(short8*)(smem + (u1 >> 2) * 36 + (u1 & 3) * 8) = s1;
        *(short8*)(smem + (u2 >> 2) * 36 + (u2 & 3) * 8) = s2;
    }
    short8 a = *(const short8*)(xrow);
    __syncthreads();

    for (int kc = 0; kc < 8; ++kc) {                 // 256 of K in chunks of 32
        const int cur = kc & 1, nxt = cur ^ 1;
        short8 p0, p1, p2, na;
        if (kc < 7) {
            p0 = *(const short8*)(Wt + (size_t)(u0 >> 2) * XSTR + kbase + (kc + 1) * 32 + (u0 & 3) * 8);
            p1 = *(const short8*)(Wt + (size_t)(u1 >> 2) * XSTR + kbase + (kc + 1) * 32 + (u1 & 3) * 8);
            p2 = *(const short8*)(Wt + (size_t)(u2 >> 2) * XSTR + kbase + (kc + 1) * 32 + (u2 & 3) * 8);
            na = *(const short8*)(xrow + (kc + 1) * 32);
        }
        const u16* base = smem + cur * 6912;
#pragma unroll
        for (int t = 0; t < 12; ++t) {
            short8 b = *(const short8*)(base + (t * 16 + l16) * 36 + koff);
            acc[t] = MFMA16(a, b, acc[t]);
        }
        if (kc < 7) {
            u16* nb = smem + nxt * 6912;
            *(short8*)(nb + (u0 >> 2) * 36 + (u0 & 3) * 8) = p0;
            *(short8*)(nb + (u1 >> 2) * 36 + (u1 & 3) * 8) = p1;
            *(short8*)(nb + (u2 >> 2) * 36 + (u2 & 3) * 8) = p2;
            __syncthreads();
            a = na;
        }
    }

    // epilogue: bounce through LDS tile [64][200], then linear contiguous store
    __syncthreads();
    const int trow = w * 16 + quad * 4;
#pragma unroll
    for (int t = 0; t < 12; ++t) {
        int col = t * 16 + l16;
#pragma unroll
        for (int reg = 0; reg < 4; ++reg)
            smem[(trow + reg) * 200 + col] = f2b(acc[t][reg]);
    }
    __syncthreads();
    u16* dst = Pp + ((size_t)kchunk * 16384 + mbase) * 192;   // 64*192 u16 contiguous
#pragma unroll
    for (int j = 0; j < 6; ++j) {
        int u = tid + j * 256;                        // 0..1535 16B-units
        int row = u / 24, rem = (u % 24) * 8;
        *(short8*)(dst + (size_t)u * 8) = *(const short8*)(smem + row * 200 + rem);
    }
}

// ---------- kernel 3: proj combine — sum 4 bf16 partials, write Kb/Qb/Vt(padded)
__global__ __launch_bounds__(256) void projc_kernel(const u16* __restrict__ Pp,
                                                    u16* __restrict__ Kb,
                                                    u16* __restrict__ Qb,
                                                    u16* __restrict__ Vt) {
    __shared__ u16 vtile[64][72];                    // [h][t_local]
    const int tid = threadIdx.x;
    const int r0 = blockIdx.x * 64;

    for (int third = 0; third < 3; ++third) {        // 0:K 1:Q 2:V
#pragma unroll
        for (int i = 0; i < 2; ++i) {
            int lin = i * 256 + tid, row = lin >> 3, cu = lin & 7;
            const u16* src = Pp + ((size_t)(r0 + row)) * 192 + third * 64 + cu * 8;
            float s[8];
#pragma unroll
            for (int j = 0; j < 8; ++j) s[j] = 0.0f;
#pragma unroll
            for (int ch = 0; ch < 4; ++ch) {
                short8 v = *(const short8*)(src + (size_t)ch * 16384 * 192);
#pragma unroll
                for (int j = 0; j < 8; ++j) s[j] += b2f((u16)v[j]);
            }
            if (third < 2) {
                u16* dst = (third == 0) ? Kb : Qb;
                short8 o;
#pragma unroll
                for (int j = 0; j < 8; ++j) o[j] = f2b(s[j]);
                *(short8*)(dst + (size_t)(r0 + row) * 64 + cu * 8) = o;
            } else {
#pragma unroll
                for (int j = 0; j < 8; ++j)
                    vtile[cu * 8 + j][row] = f2b(s[j]);
            }
        }
    }
    __syncthreads();
    const int b = r0 >> 12, t0b = r0 & 4095;
#pragma unroll
    for (int i = 0; i < 2; ++i) {
        int lin = i * 256 + tid, h = lin >> 3, c8 = (lin & 7) << 3;
        *(short8*)(Vt + (size_t)(b * 64 + h) * VSTR + t0b + c8) = *(short8*)&vtile[h][c8];
    }
}

// ---------- kernel 4: split-S flash attention, max-free softmax, padded Vt.
__global__ __launch_bounds__(256) void attn_kernel(const u16* __restrict__ Kb,
                                                   const u16* __restrict__ Qb,
                                                   const u16* __restrict__ Vt,
                                                   u16* __restrict__ Op,
                                                   float* __restrict__ Ml) {
    const int tile = blockIdx.x, chunk = blockIdx.y, b = blockIdx.z;
    if (chunk * 8 > tile) return;
    __shared__ u16 Qs[64 * 64];                      // unpadded: contiguous staging writes
    __shared__ u16 Vs[64 * 64];
    __shared__ u16 Ps[4][16][72];
    const int tid = threadIdx.x;
    const int w = tid >> 6, lane = tid & 63, quad = lane >> 4, l16 = lane & 15;
    const int t0 = tile * 64;
    const int stBeg = chunk * 8;
    const int stEnd = min(chunk * 8 + 7, tile);

    const int lin0 = tid, lin1 = tid + 256;          // flat staging: dst = lin*8 u16
    const size_t vrow0 = (size_t)(b * 64 + (lin0 >> 3)) * VSTR + (lin0 & 7) * 8;
    const size_t vrow1 = (size_t)(b * 64 + (lin1 >> 3)) * VSTR + (lin1 & 7) * 8;

    short8 aK[2];
#pragma unroll
    for (int kk = 0; kk < 2; ++kk)
        aK[kk] = *(const short8*)(Kb + (size_t)((b << 12) + t0 + w * 16 + l16) * 64 + kk * 32 + quad * 8);

    short8 qr0 = *(const short8*)(Qb + (size_t)((b << 12) + stBeg * 64) * 64 + lin0 * 8);
    short8 qr1 = *(const short8*)(Qb + (size_t)((b << 12) + stBeg * 64) * 64 + lin1 * 8);
    short8 vr0 = *(const short8*)(Vt + vrow0 + stBeg * 64);
    short8 vr1 = *(const short8*)(Vt + vrow1 + stBeg * 64);

    float l_s[4] = {0.0f, 0.0f, 0.0f, 0.0f};
    f32x4 O[4];
#pragma unroll
    for (int nt = 0; nt < 4; ++nt) O[nt] = (f32x4)(0.0f);

    const int trow = w * 16 + quad * 4;
    const int tglob = t0 + trow;

    for (int st = stBeg; st <= stEnd; ++st) {
        const int s0 = st * 64;
        __syncthreads();                              // prev tile's LDS reads done
        *(short8*)(Qs + lin0 * 8) = qr0;
        *(short8*)(Qs + lin1 * 8) = qr1;
        *(short8*)(Vs + lin0 * 8) = vr0;
        *(short8*)(Vs + lin1 * 8) = vr1;
        __syncthreads();
        if (st < stEnd) {                             // next-tile loads fly during compute
            qr0 = *(const short8*)(Qb + (size_t)((b << 12) + (st + 1) * 64) * 64 + lin0 * 8);
            qr1 = *(const short8*)(Qb + (size_t)((b << 12) + (st + 1) * 64) * 64 + lin1 * 8);
            vr0 = *(const short8*)(Vt + vrow0 + (st + 1) * 64);
            vr1 = *(const short8*)(Vt + vrow1 + (st + 1) * 64);
        }

        // S = K @ Q^T
        f32x4 sc[4];
#pragma unroll
        for (int nt = 0; nt < 4; ++nt) sc[nt] = (f32x4)(0.0f);
#pragma unroll
        for (int kk = 0; kk < 2; ++kk)
#pragma unroll
            for (int nt = 0; nt < 4; ++nt) {
                short8 bq = *(const short8*)(Qs + (nt * 16 + l16) * 64 + kk * 32 + quad * 8);
                sc[nt] = MFMA16(aK[kk], bq, sc[nt]);
            }

        // max-free softmax: p = exp(s/8); masked -> exp(-huge) = 0
        float rs[4] = {0.0f, 0.0f, 0.0f, 0.0f};
#pragma unroll
        for (int nt = 0; nt < 4; ++nt) {
            int sg = s0 + nt * 16 + l16;
#pragma unroll
            for (int reg = 0; reg < 4; ++reg) {
                float v = sc[nt][reg] * 0.125f;
                if (st == tile && sg > tglob + reg) v = -1e30f;
                float p = __expf(v);
                rs[reg] += p;
                Ps[w][quad * 4 + reg][nt * 16 + l16] = f2b(p);
            }
        }
#pragma unroll
        for (int reg = 0; reg < 4; ++reg) {
            float v = rs[reg];
            v += __shfl_xor(v, 1);
            v += __shfl_xor(v, 2);
            v += __shfl_xor(v, 4);
            v += __shfl_xor(v, 8);
            l_s[reg] += v;
        }

        // PV (Ps is wave-private; same-wave DS ordering suffices)
#pragma unroll
        for (int kk = 0; kk < 2; ++kk) {
            short8 ap = *(const short8*)&Ps[w][l16][kk * 32 + quad * 8];
#pragma unroll
            for (int nt = 0; nt < 4; ++nt) {
                short8 bv = *(const short8*)(Vs + (nt * 16 + l16) * 64 + kk * 32 + quad * 8);
                O[nt] = MFMA16(ap, bv, O[nt]);
            }
        }
    }

    const int slot = ((b * 64 + tile) * 8 + chunk);
    if (l16 == 0) {
#pragma unroll
        for (int reg = 0; reg < 4; ++reg)
            Ml[(size_t)slot * 64 + trow + reg] = l_s[reg];
    }
#pragma unroll
    for (int nt = 0; nt < 4; ++nt)
#pragma unroll
        for (int reg = 0; reg < 4; ++reg)
            Op[(size_t)slot * 4096 + (size_t)(trow + reg) * 64 + nt * 16 + l16] = f2b(O[nt][reg]);
}

// ---------- kernel 5: combine — plain sums, divide
__global__ __launch_bounds__(256) void combine_kernel(const u16* __restrict__ Op,
                                                      const float* __restrict__ Ml,
                                                      float* __restrict__ out) {
    const int tid = threadIdx.x, cu = tid & 7, r0 = tid >> 3;
    const int tile = blockIdx.x, b = blockIdx.y;
    const int nch = tile / 8 + 1;
    const int slotBase = (b * 64 + tile) * 8;
#pragma unroll
    for (int i = 0; i < 2; ++i) {
        const int row = r0 + 32 * i;
        float L = 0.0f, acc[8];
#pragma unroll
        for (int j = 0; j < 8; ++j) acc[j] = 0.0f;
#pragma unroll
        for (int c = 0; c < 8; ++c) {
            const bool act = c < nch;
            float lraw = Ml[(size_t)(slotBase + c) * 64 + row];
            short8 ov = *(const short8*)(Op + (size_t)(slotBase + c) * 4096 + (size_t)row * 64 + cu * 8);
            L += act ? lraw : 0.0f;
#pragma unroll
            for (int j = 0; j < 8; ++j)
                acc[j] += act ? b2f((u16)ov[j]) : 0.0f;
        }
        float inv = 1.0f / L;
        float* dst = out + ((size_t)(b << 12) + tile * 64 + row) * 64 + cu * 8;
        *(float4*)(dst)     = make_float4(acc[0] * inv, acc[1] * inv, acc[2] * inv, acc[3] * inv);
        *(float4*)(dst + 4) = make_float4(acc[4] * inv, acc[5] * inv, acc[6] * inv, acc[7] * inv);
    }
}

extern "C" void kernel_launch(void* const* d_in, const int* in_sizes, int n_in,
                              void* d_out, int out_size, void* d_ws, size_t ws_size,
                              hipStream_t stream) {
    const float* x  = (const float*)d_in[0];
    const float* Wk = (const float*)d_in[1];
    const float* Wq = (const float*)d_in[2];
    const float* Wv = (const float*)d_in[3];

    u16* ws16 = (u16*)d_ws;
    u16* Wt = ws16;                          // 192*1048   = 201,216 u16
    u16* Kb = Wt + 201216;                   // 1,048,576
    u16* Qb = Kb + 1048576;                  // 1,048,576
    u16* Vt = Qb + 1048576;                  // 4*64*4120  = 1,054,720
    u16* xb = Vt + 1054720;                  // 16384*1048 = 17,170,432 (34.3 MB)
    u16* Pp = xb + 17170432;                 // 4*16384*192 = 12,582,912 (25.2 MB)
    u16* Op = xb;                            // aliases xb (dead after proj1): 8,388,608
    float* Ml = (float*)(Op + 8388608);      // 131,072 f32 (inside xb region)
    // total ws ~66.2 MB; aliasing safe: proj1 reads xb before attn writes Op/Ml.

    xconv_kernel<<<2048, 256, 0, stream>>>(x, xb);
    wt_kernel<<<48, 256, 0, stream>>>(Wk, Wq, Wv, Wt);
    proj1_kernel<<<1024, 256, 0, stream>>>(xb, Wt, Pp);
    projc_kernel<<<256, 256, 0, stream>>>(Pp, Kb, Qb, Vt);
    attn_kernel<<<dim3(64, 8, 4), 256, 0, stream>>>(Kb, Qb, Vt, Op, Ml);
    combine_kernel<<<dim3(64, 4), 256, 0, stream>>>(Op, Ml, (float*)d_out);
}

// Round 10
// 196.788 us; speedup vs baseline: 1.0950x; 1.0950x over previous
//
#include <hip/hip_runtime.h>

// Head attention, B=4 T=4096 C=1024 H=64. f32 in/out, bf16 MFMA compute.
// scores = k @ q^T (reference quirk).
// Counter-backed design rules:
//  - intra-block operand reuse through LDS (r4)
//  - stride padding / segment size / L3-residency of private data: all neutral (r5-r9)
//  - HYPOTHESIS under test: lockstep broadcast reads of shared lines serialize in
//    L2/L3 -> replicate shared operands (Wt x8, Q/V x4) and spread readers.

typedef __attribute__((ext_vector_type(8))) short short8;
typedef __attribute__((ext_vector_type(4))) float f32x4;
typedef unsigned short u16;

#define MFMA16(A, B, C) __builtin_amdgcn_mfma_f32_16x16x32_bf16((A), (B), (C), 0, 0, 0)

__device__ __forceinline__ u16 f2b(float f) {
    unsigned int u = __builtin_bit_cast(unsigned int, f);
    u += 0x7fffu + ((u >> 16) & 1u);
    return (u16)(u >> 16);
}
__device__ __forceinline__ float b2f(u16 v) {
    return __builtin_bit_cast(float, (unsigned int)v << 16);
}

// ---------- kernel 1: W convert+transpose -> Wt[8 replicas][192][1024] bf16
__global__ __launch_bounds__(256) void wt_kernel(const float* __restrict__ Wk,
                                                 const float* __restrict__ Wq,
                                                 const float* __restrict__ Wv,
                                                 u16* __restrict__ Wt) {
    __shared__ u16 t[64][65];
    const int mat = blockIdx.x >> 4;
    const int rt  = blockIdx.x & 15;
    const float* W = (mat == 0) ? Wk : (mat == 1 ? Wq : Wv);
    const int tid = threadIdx.x;
#pragma unroll
    for (int i = 0; i < 16; ++i) {
        int lin = i * 256 + tid, r = lin >> 6, c = lin & 63;
        t[c][r] = f2b(W[(size_t)(rt * 64 + r) * 64 + c]);
    }
    __syncthreads();
    for (int rep = 0; rep < 8; ++rep) {
#pragma unroll
        for (int i = 0; i < 16; ++i) {
            int lin = i * 256 + tid, n = lin >> 6, k = lin & 63;
            Wt[(size_t)rep * 196608 + (size_t)(mat * 64 + n) * 1024 + rt * 64 + k] = t[n][k];
        }
    }
}

// ---------- kernel 2: fused projection, full K per block, replicated Wt.
// 256 blocks x 64 rows; double-buffered Wt LDS staging; direct Kb/Qb(x4)/Vt(x4) epilogue.
__global__ __launch_bounds__(256) void proj_kernel(const float* __restrict__ x,
                                                   const u16* __restrict__ Wt,
                                                   u16* __restrict__ Kb,
                                                   u16* __restrict__ Qb,
                                                   u16* __restrict__ Vt) {
    __shared__ u16 smem[2 * 192 * 36];               // 27.6 KB (also epilogue tile)
    const int tid = threadIdx.x;
    const int w = tid >> 6, lane = tid & 63, quad = lane >> 4, l16 = lane & 15;
    const int mgroup = blockIdx.x;
    const int mbase = mgroup * 64;
    const int m = mbase + w * 16 + l16;
    const int koff = quad * 8;
    const u16* Wtr = Wt + (size_t)(mgroup & 7) * 196608;   // replica: spread readers

    f32x4 acc[12];
#pragma unroll
    for (int t = 0; t < 12; ++t) acc[t] = (f32x4)(0.0f);

    const float* xrow = x + (size_t)m * 1024 + koff;
    const int u0 = tid, u1 = tid + 256, u2 = tid + 512;  // 768 16B-units = [192][32]

    {   // stage kc=0 into buf 0
        short8 s0 = *(const short8*)(Wtr + (size_t)(u0 >> 2) * 1024 + (u0 & 3) * 8);
        short8 s1 = *(const short8*)(Wtr + (size_t)(u1 >> 2) * 1024 + (u1 & 3) * 8);
        short8 s2 = *(const short8*)(Wtr + (size_t)(u2 >> 2) * 1024 + (u2 & 3) * 8);
        *(short8*)(smem + (u0 >> 2) * 36 + (u0 & 3) * 8) = s0;
        *(short8*)(smem + (u1 >> 2) * 36 + (u1 & 3) * 8) = s1;
        *(short8*)(smem + (u2 >> 2) * 36 + (u2 & 3) * 8) = s2;
    }
    float4 c0 = *(const float4*)(xrow);
    float4 c1 = *(const float4*)(xrow + 4);
    __syncthreads();

    for (int kc = 0; kc < 32; ++kc) {                // K = 1024 in chunks of 32
        const int cur = kc & 1, nxt = cur ^ 1;
        short8 p0, p1, p2;
        float4 n0, n1;
        if (kc < 31) {
            p0 = *(const short8*)(Wtr + (size_t)(u0 >> 2) * 1024 + (kc + 1) * 32 + (u0 & 3) * 8);
            p1 = *(const short8*)(Wtr + (size_t)(u1 >> 2) * 1024 + (kc + 1) * 32 + (u1 & 3) * 8);
            p2 = *(const short8*)(Wtr + (size_t)(u2 >> 2) * 1024 + (kc + 1) * 32 + (u2 & 3) * 8);
            n0 = *(const float4*)(xrow + (kc + 1) * 32);
            n1 = *(const float4*)(xrow + (kc + 1) * 32 + 4);
        }
        short8 a;
        a[0] = f2b(c0.x); a[1] = f2b(c0.y); a[2] = f2b(c0.z); a[3] = f2b(c0.w);
        a[4] = f2b(c1.x); a[5] = f2b(c1.y); a[6] = f2b(c1.z); a[7] = f2b(c1.w);
        const u16* base = smem + cur * 6912;
#pragma unroll
        for (int t = 0; t < 12; ++t) {
            short8 b = *(const short8*)(base + (t * 16 + l16) * 36 + koff);
            acc[t] = MFMA16(a, b, acc[t]);
        }
        if (kc < 31) {
            u16* nb = smem + nxt * 6912;
            *(short8*)(nb + (u0 >> 2) * 36 + (u0 & 3) * 8) = p0;
            *(short8*)(nb + (u1 >> 2) * 36 + (u1 & 3) * 8) = p1;
            *(short8*)(nb + (u2 >> 2) * 36 + (u2 & 3) * 8) = p2;
            __syncthreads();
            c0 = n0; c1 = n1;
        }
    }

    // epilogue: LDS bounce, write Kb, 4x Qb replicas, 4x Vt replicas
    u16 (*tile)[72] = (u16(*)[72])smem;
    const int trow = w * 16 + quad * 4;
    for (int p = 0; p < 2; ++p) {
        __syncthreads();
#pragma unroll
        for (int nt = 0; nt < 4; ++nt)
#pragma unroll
            for (int reg = 0; reg < 4; ++reg)
                tile[trow + reg][nt * 16 + l16] = f2b(acc[p * 4 + nt][reg]);
        __syncthreads();
#pragma unroll
        for (int c = 0; c < 2; ++c) {
            int lin = tid + c * 256;
            int row = lin >> 3, cu8 = (lin & 7) << 3;
            short8 v = *(const short8*)&tile[row][cu8];
            if (p == 0) {
                *(short8*)(Kb + (size_t)(mbase + row) * 64 + cu8) = v;
            } else {
#pragma unroll
                for (int r = 0; r < 4; ++r)
                    *(short8*)(Qb + (size_t)r * 1048576 + (size_t)(mbase + row) * 64 + cu8) = v;
            }
        }
    }
    __syncthreads();
#pragma unroll
    for (int nt = 0; nt < 4; ++nt)
#pragma unroll
        for (int reg = 0; reg < 4; ++reg)
            tile[nt * 16 + l16][trow + reg] = f2b(acc[8 + nt][reg]);
    __syncthreads();
    const int b = mbase >> 12, t0b = mbase & 4095;
#pragma unroll
    for (int c = 0; c < 2; ++c) {
        int lin = tid + c * 256;
        int h = lin >> 3, c8 = (lin & 7) << 3;
        short8 v = *(const short8*)&tile[h][c8];
#pragma unroll
        for (int r = 0; r < 4; ++r)
            *(short8*)(Vt + (size_t)r * 1048576 + ((size_t)(b * 64 + h) << 12) + t0b + c8) = v;
    }
}

// ---------- kernel 3: split-S flash attention, max-free softmax, replicated Q/V.
__global__ __launch_bounds__(256) void attn_kernel(const u16* __restrict__ Kb,
                                                   const u16* __restrict__ Qb,
                                                   const u16* __restrict__ Vt,
                                                   u16* __restrict__ Op,
                                                   float* __restrict__ Ml) {
    const int tile = blockIdx.x, chunk = blockIdx.y, b = blockIdx.z;
    if (chunk * 8 > tile) return;
    __shared__ u16 Qs[64 * 64];                      // unpadded: contiguous staging writes
    __shared__ u16 Vs[64 * 64];
    __shared__ u16 Ps[4][16][72];
    const int tid = threadIdx.x;
    const int w = tid >> 6, lane = tid & 63, quad = lane >> 4, l16 = lane & 15;
    const int t0 = tile * 64;
    const int stBeg = chunk * 8;
    const int stEnd = min(chunk * 8 + 7, tile);

    // replica index: simultaneous readers of an s-tile differ in `tile` -> spread x4
    const u16* Qp = Qb + (size_t)(tile & 3) * 1048576;
    const u16* Vp = Vt + (size_t)(tile & 3) * 1048576;

    const int lin0 = tid, lin1 = tid + 256;          // flat staging: dst = lin*8 u16
    const size_t vrow0 = ((size_t)(b * 64 + (lin0 >> 3)) << 12) + (lin0 & 7) * 8;
    const size_t vrow1 = ((size_t)(b * 64 + (lin1 >> 3)) << 12) + (lin1 & 7) * 8;

    short8 aK[2];
#pragma unroll
    for (int kk = 0; kk < 2; ++kk)
        aK[kk] = *(const short8*)(Kb + (size_t)((b << 12) + t0 + w * 16 + l16) * 64 + kk * 32 + quad * 8);

    short8 qr0 = *(const short8*)(Qp + (size_t)((b << 12) + stBeg * 64) * 64 + lin0 * 8);
    short8 qr1 = *(const short8*)(Qp + (size_t)((b << 12) + stBeg * 64) * 64 + lin1 * 8);
    short8 vr0 = *(const short8*)(Vp + vrow0 + stBeg * 64);
    short8 vr1 = *(const short8*)(Vp + vrow1 + stBeg * 64);

    float l_s[4] = {0.0f, 0.0f, 0.0f, 0.0f};
    f32x4 O[4];
#pragma unroll
    for (int nt = 0; nt < 4; ++nt) O[nt] = (f32x4)(0.0f);

    const int trow = w * 16 + quad * 4;
    const int tglob = t0 + trow;

    for (int st = stBeg; st <= stEnd; ++st) {
        const int s0 = st * 64;
        __syncthreads();                              // prev tile's LDS reads done
        *(short8*)(Qs + lin0 * 8) = qr0;
        *(short8*)(Qs + lin1 * 8) = qr1;
        *(short8*)(Vs + lin0 * 8) = vr0;
        *(short8*)(Vs + lin1 * 8) = vr1;
        __syncthreads();
        if (st < stEnd) {                             // next-tile loads fly during compute
            qr0 = *(const short8*)(Qp + (size_t)((b << 12) + (st + 1) * 64) * 64 + lin0 * 8);
            qr1 = *(const short8*)(Qp + (size_t)((b << 12) + (st + 1) * 64) * 64 + lin1 * 8);
            vr0 = *(const short8*)(Vp + vrow0 + (st + 1) * 64);
            vr1 = *(const short8*)(Vp + vrow1 + (st + 1) * 64);
        }

        // S = K @ Q^T
        f32x4 sc[4];
#pragma unroll
        for (int nt = 0; nt < 4; ++nt) sc[nt] = (f32x4)(0.0f);
#pragma unroll
        for (int kk = 0; kk < 2; ++kk)
#pragma unroll
            for (int nt = 0; nt < 4; ++nt) {
                short8 bq = *(const short8*)(Qs + (nt * 16 + l16) * 64 + kk * 32 + quad * 8);
                sc[nt] = MFMA16(aK[kk], bq, sc[nt]);
            }

        // max-free softmax: p = exp(s/8); masked -> exp(-huge) = 0
        float rs[4] = {0.0f, 0.0f, 0.0f, 0.0f};
#pragma unroll
        for (int nt = 0; nt < 4; ++nt) {
            int sg = s0 + nt * 16 + l16;
#pragma unroll
            for (int reg = 0; reg < 4; ++reg) {
                float v = sc[nt][reg] * 0.125f;
                if (st == tile && sg > tglob + reg) v = -1e30f;
                float p = __expf(v);
                rs[reg] += p;
                Ps[w][quad * 4 + reg][nt * 16 + l16] = f2b(p);
            }
        }
#pragma unroll
        for (int reg = 0; reg < 4; ++reg) {
            float v = rs[reg];
            v += __shfl_xor(v, 1);
            v += __shfl_xor(v, 2);
            v += __shfl_xor(v, 4);
            v += __shfl_xor(v, 8);
            l_s[reg] += v;
        }

        // PV (Ps is wave-private; same-wave DS ordering suffices)
#pragma unroll
        for (int kk = 0; kk < 2; ++kk) {
            short8 ap = *(const short8*)&Ps[w][l16][kk * 32 + quad * 8];
#pragma unroll
            for (int nt = 0; nt < 4; ++nt) {
                short8 bv = *(const short8*)(Vs + (nt * 16 + l16) * 64 + kk * 32 + quad * 8);
                O[nt] = MFMA16(ap, bv, O[nt]);
            }
        }
    }

    const int slot = ((b * 64 + tile) * 8 + chunk);
    if (l16 == 0) {
#pragma unroll
        for (int reg = 0; reg < 4; ++reg)
            Ml[(size_t)slot * 64 + trow + reg] = l_s[reg];
    }
#pragma unroll
    for (int nt = 0; nt < 4; ++nt)
#pragma unroll
        for (int reg = 0; reg < 4; ++reg)
            Op[(size_t)slot * 4096 + (size_t)(trow + reg) * 64 + nt * 16 + l16] = f2b(O[nt][reg]);
}

// ---------- kernel 4: combine — plain sums, divide
__global__ __launch_bounds__(256) void combine_kernel(const u16* __restrict__ Op,
                                                      const float* __restrict__ Ml,
                                                      float* __restrict__ out) {
    const int tid = threadIdx.x, cu = tid & 7, r0 = tid >> 3;
    const int tile = blockIdx.x, b = blockIdx.y;
    const int nch = tile / 8 + 1;
    const int slotBase = (b * 64 + tile) * 8;
#pragma unroll
    for (int i = 0; i < 2; ++i) {
        const int row = r0 + 32 * i;
        float L = 0.0f, acc[8];
#pragma unroll
        for (int j = 0; j < 8; ++j) acc[j] = 0.0f;
#pragma unroll
        for (int c = 0; c < 8; ++c) {
            const bool act = c < nch;
            float lraw = Ml[(size_t)(slotBase + c) * 64 + row];
            short8 ov = *(const short8*)(Op + (size_t)(slotBase + c) * 4096 + (size_t)row * 64 + cu * 8);
            L += act ? lraw : 0.0f;
#pragma unroll
            for (int j = 0; j < 8; ++j)
                acc[j] += act ? b2f((u16)ov[j]) : 0.0f;
        }
        float inv = 1.0f / L;
        float* dst = out + ((size_t)(b << 12) + tile * 64 + row) * 64 + cu * 8;
        *(float4*)(dst)     = make_float4(acc[0] * inv, acc[1] * inv, acc[2] * inv, acc[3] * inv);
        *(float4*)(dst + 4) = make_float4(acc[4] * inv, acc[5] * inv, acc[6] * inv, acc[7] * inv);
    }
}

extern "C" void kernel_launch(void* const* d_in, const int* in_sizes, int n_in,
                              void* d_out, int out_size, void* d_ws, size_t ws_size,
                              hipStream_t stream) {
    const float* x  = (const float*)d_in[0];
    const float* Wk = (const float*)d_in[1];
    const float* Wq = (const float*)d_in[2];
    const float* Wv = (const float*)d_in[3];

    u16* ws16 = (u16*)d_ws;
    u16* Wt = ws16;                          // 8 * 196608  = 1,572,864 u16 (3.1 MB)
    u16* Kb = Wt + 1572864;                  // 1,048,576          (2 MB)
    u16* Qb = Kb + 1048576;                  // 4 * 1,048,576      (8 MB, replicas)
    u16* Vt = Qb + 4194304;                  // 4 * 1,048,576      (8 MB, replicas)
    u16* Op = Vt + 4194304;                  // 8,388,608          (16.8 MB)
    float* Ml = (float*)(Op + 8388608);      // 131,072 f32        (0.5 MB)
    // total ws ~38.6 MB

    wt_kernel<<<48, 256, 0, stream>>>(Wk, Wq, Wv, Wt);
    proj_kernel<<<256, 256, 0, stream>>>(x, Wt, Kb, Qb, Vt);
    attn_kernel<<<dim3(64, 8, 4), 256, 0, stream>>>(Kb, Qb, Vt, Op, Ml);
    combine_kernel<<<dim3(64, 4), 256, 0, stream>>>(Op, Ml, (float*)d_out);
}